// Round 6
// baseline (463.073 us; speedup 1.0000x reference)
//
#include <hip/hip_runtime.h>
#include <hip/hip_bf16.h>
#include <stdint.h>

#define SEQ 4096
#define DM 2048
#define NH 16
#define HD 128

typedef __attribute__((ext_vector_type(4)))  float f32x4;
typedef __attribute__((ext_vector_type(16))) float f32x16;
typedef __attribute__((ext_vector_type(8)))  short bf16x8;
typedef __attribute__((ext_vector_type(4)))  float float4_t;
typedef __attribute__((ext_vector_type(4)))  short s16x4;
typedef __attribute__((ext_vector_type(2)))  int   i32x2;
typedef __attribute__((ext_vector_type(2)))  unsigned u32x2;

__device__ __forceinline__ short f2bf(float f) {
  union { float f; unsigned u; } c; c.f = f;
  unsigned u = c.u;
  u += 0x7FFFu + ((u >> 16) & 1u);   // RNE
  return (short)(u >> 16);
}

__device__ __forceinline__ int cvtpk(float lo, float hi) {
  int r;
  asm("v_cvt_pk_bf16_f32 %0, %1, %2" : "=v"(r) : "v"(lo), "v"(hi));
  return r;
}

__device__ __forceinline__ float exp2r(float x) {   // raw v_exp_f32
  return __builtin_amdgcn_exp2f(x);
}

__device__ __forceinline__ void async16(const void* g, void* l) {
  __builtin_amdgcn_global_load_lds((const __attribute__((address_space(1))) void*)g,
                                   (__attribute__((address_space(3))) void*)l, 16, 0, 0);
}

__global__ __launch_bounds__(256) void rope_tables_kernel(float2* __restrict__ tab) {
  int idx = blockIdx.x * 256 + threadIdx.x;  // SEQ*64
  int s = idx >> 6, j = idx & 63;
  float invf = expf(-(float)j * (9.210340371976184f / 64.0f)); // 10000^(-j/64)
  float ang = (float)s * invf;
  tab[idx] = make_float2(cosf(ang), sinf(ang));
}

__global__ __launch_bounds__(256) void f32_to_bf16_kernel(const float* __restrict__ in,
                                                          short* __restrict__ out, int n4) {
  int stride = gridDim.x * 256;
  for (int i = blockIdx.x * 256 + threadIdx.x; i < n4; i += stride) {
    float4_t v = ((const float4_t*)in)[i];
    s16x4 r;
    #pragma unroll
    for (int u = 0; u < 4; u++) r[u] = f2bf(v[u]);
    ((s16x4*)out)[i] = r;
  }
}

// ---------------- GEMM: bf16 in, global_load_lds staging, BK=64 ------------
// C[M][N] = A[M][K] * B[N][K]^T. OUT_MODE: 0 f32, 2 bf16 transposed.
template<int OUT_MODE>
__global__ __launch_bounds__(256) void gemm_async_kernel(
    const short* __restrict__ A, const short* __restrict__ B,
    void* __restrict__ Cp, int M, int N, int K) {
  __shared__ short As[128 * 64];
  __shared__ short Bs[128 * 64];
  const int t = threadIdx.x, lane = t & 63, w = t >> 6;
  const int wr = w >> 1, wc = w & 1;
  const size_t Mbase = (size_t)blockIdx.x * 128;
  const size_t Nbase = (size_t)blockIdx.y * 128;
  f32x4 acc[4][4] = {};

  for (int k0 = 0; k0 < K; k0 += 64) {
    __syncthreads();
    #pragma unroll
    for (int c = 0; c < 4; c++) {
      int ob = w * 4096 + c * 1024;           // uniform per wave
      int o = ob + lane * 16;
      int row = o >> 7;
      int cb = (o & 127) ^ ((row & 7) << 4);
      async16((const char*)A + ((Mbase + row) * (size_t)K + k0) * 2 + cb, (char*)As + ob);
      async16((const char*)B + ((Nbase + row) * (size_t)K + k0) * 2 + cb, (char*)Bs + ob);
    }
    __syncthreads();

    bf16x8 a[2][4], b[2][4];
    #pragma unroll
    for (int ks = 0; ks < 2; ks++) {
      #pragma unroll
      for (int m = 0; m < 4; m++) {
        int row = wr * 64 + m * 16 + (lane & 15);
        int chunk = ks * 64 + (lane >> 4) * 16;
        a[ks][m] = *(const bf16x8*)((const char*)As + row * 128 + (chunk ^ ((row & 7) << 4)));
      }
      #pragma unroll
      for (int n = 0; n < 4; n++) {
        int row = wc * 64 + n * 16 + (lane & 15);
        int chunk = ks * 64 + (lane >> 4) * 16;
        b[ks][n] = *(const bf16x8*)((const char*)Bs + row * 128 + (chunk ^ ((row & 7) << 4)));
      }
    }
    #pragma unroll
    for (int ks = 0; ks < 2; ks++)
      #pragma unroll
      for (int m = 0; m < 4; m++)
        #pragma unroll
        for (int n = 0; n < 4; n++)
          acc[m][n] = __builtin_amdgcn_mfma_f32_16x16x32_bf16(a[ks][m], b[ks][n], acc[m][n], 0, 0, 0);
  }

  #pragma unroll
  for (int m = 0; m < 4; m++)
    #pragma unroll
    for (int n = 0; n < 4; n++)
      #pragma unroll
      for (int j = 0; j < 4; j++) {
        size_t row = Mbase + wr * 64 + m * 16 + (lane >> 4) * 4 + j;
        size_t col = Nbase + wc * 64 + n * 16 + (lane & 15);
        float v = acc[m][n][j];
        if (OUT_MODE == 0) ((float*)Cp)[row * N + col] = v;
        else               ((short*)Cp)[col * (size_t)M + row] = f2bf(v);
      }
}

// ---------------- GEMM + fused RoPE epilogue (Q/K projections) -------------
// Wave tiling 4x1: wave w owns rows w*32..w*32+31, all 128 cols (one head).
// IS_Q folds log2e/sqrt(HD) into Q so attention works in exp2 domain.
template<int IS_Q>
__global__ __launch_bounds__(256) void gemm_rope_kernel(
    const short* __restrict__ A, const short* __restrict__ B,
    short* __restrict__ C, const float2* __restrict__ tab) {
  __shared__ short As[128 * 64];
  __shared__ short Bs[128 * 64];
  const int t = threadIdx.x, lane = t & 63, w = t >> 6;
  const size_t Mbase = (size_t)blockIdx.x * 128;
  const size_t Nbase = (size_t)blockIdx.y * 128;
  const int K = DM;
  f32x4 acc[2][8] = {};

  for (int k0 = 0; k0 < K; k0 += 64) {
    __syncthreads();
    #pragma unroll
    for (int c = 0; c < 4; c++) {
      int ob = w * 4096 + c * 1024;
      int o = ob + lane * 16;
      int row = o >> 7;
      int cb = (o & 127) ^ ((row & 7) << 4);
      async16((const char*)A + ((Mbase + row) * (size_t)K + k0) * 2 + cb, (char*)As + ob);
      async16((const char*)B + ((Nbase + row) * (size_t)K + k0) * 2 + cb, (char*)Bs + ob);
    }
    __syncthreads();

    bf16x8 a[2][2], b[2][8];
    #pragma unroll
    for (int ks = 0; ks < 2; ks++) {
      #pragma unroll
      for (int m = 0; m < 2; m++) {
        int row = w * 32 + m * 16 + (lane & 15);
        int chunk = ks * 64 + (lane >> 4) * 16;
        a[ks][m] = *(const bf16x8*)((const char*)As + row * 128 + (chunk ^ ((row & 7) << 4)));
      }
      #pragma unroll
      for (int n = 0; n < 8; n++) {
        int row = n * 16 + (lane & 15);
        int chunk = ks * 64 + (lane >> 4) * 16;
        b[ks][n] = *(const bf16x8*)((const char*)Bs + row * 128 + (chunk ^ ((row & 7) << 4)));
      }
    }
    #pragma unroll
    for (int ks = 0; ks < 2; ks++)
      #pragma unroll
      for (int m = 0; m < 2; m++)
        #pragma unroll
        for (int n = 0; n < 8; n++)
          acc[m][n] = __builtin_amdgcn_mfma_f32_16x16x32_bf16(a[ks][m], b[ks][n], acc[m][n], 0, 0, 0);
  }

  // Q: scale = log2(e)/sqrt(128) so attention uses exp2 directly.
  const float SC = IS_Q ? 0.12751746f : 1.0f;
  #pragma unroll
  for (int m = 0; m < 2; m++)
    #pragma unroll
    for (int n = 0; n < 4; n++)
      #pragma unroll
      for (int j = 0; j < 4; j++) {
        int row = (int)Mbase + w * 32 + m * 16 + (lane >> 4) * 4 + j;   // seq pos
        int dj = n * 16 + (lane & 15);                                  // 0..63
        float2 cs = tab[row * 64 + dj];
        float cc = cs.x * SC, ss = cs.y * SC;
        float r1 = acc[m][n][j], r2 = acc[m][n + 4][j];
        C[(size_t)row * DM + Nbase + dj]      = f2bf(r1 * cc - r2 * ss);
        C[(size_t)row * DM + Nbase + dj + 64] = f2bf(r2 * cc + r1 * ss);
      }
}

// ---------------- flash attention v5: 16 waves, QBLK=128, kv-quarters ------
// 1024 threads = 4 q-strips (32 rows) x 4 kv-quarters (32 keys of KVBLK=128).
// Each wave keeps a partial (m,l,oacc); quarters merge via 2-round LDS merge.
// Pairs (p, 31-p): every block = 33 kv-steps. Grid 256 = 1/CU, 4 waves/SIMD.
// Q pre-scaled by log2e/sqrt(HD) (exp2 domain). VT is [DM][SEQ].
// S^T = mfma(K,Q); O^T = mfma(VT,P^T).
__global__ __launch_bounds__(1024, 4) void flash_attn5_kernel(
    const short* __restrict__ Q, const short* __restrict__ K,
    const short* __restrict__ VT, short* __restrict__ O) {
  // LDS: buf b: K at b*65536 (32KB, 128 rows x 256B), V^T at 32768+b*65536
  // (32KB, 128 d-rows x 256B). Merge overlay: region r = [r*65536, +64KB)
  // as [4 strip][128 d][32 q] fp32; ml slots at 131072 + r*1024.
  __shared__ __align__(16) char LB[133120];
  const int t = threadIdx.x, lane = t & 63, w = t >> 6;   // w: 0..15
  const int hi = lane >> 5, c31 = lane & 31;
  const int s = w & 3, v = w >> 2;                // strip, kv-quarter
  const int id = blockIdx.x;                      // 0..255
  const int h  = (id & 7) * 2 + ((id >> 3) & 1);  // 2 heads per XCD
  const int pr = id >> 4;                         // 0..15

  auto stage = [&](int kt, int buf) {
    #pragma unroll
    for (int it = 0; it < 2; it++) {
      const int ob = w * 2048 + it * 1024;        // wave-uniform LDS byte base
      const int o  = ob + lane * 16;
      const int row = o >> 8;
      const int xs = (o & 255) ^ ((row & 15) << 4);
      async16((const char*)K + ((size_t)(kt * 128 + row) * DM + h * HD) * 2 + xs,
              LB + buf * 65536 + ob);
      async16((const char*)VT + ((size_t)(h * HD + row) * SEQ + (size_t)kt * 128) * 2 + xs,
              LB + 32768 + buf * 65536 + ob);
    }
  };

  for (int rep = 0; rep < 2; rep++) {
    const int qt = rep ? (31 - pr) : pr;        // 128-row q-tile; single cover
    const int q0 = qt * 128;
    const int nt = qt + 1;
    const int qrow = q0 + s * 32 + c31;         // this lane's q-row

    __syncthreads();                            // prior rep's merge reads done
    stage(0, 0);

    // Q fragments (B-operand): lane holds Q[qrow][16ss+8hi .. +7]
    bf16x8 qf[8];
    #pragma unroll
    for (int ss = 0; ss < 8; ss++)
      qf[ss] = *(const bf16x8*)(Q + (size_t)qrow * DM + h * HD + ss * 16 + hi * 8);

    f32x16 oacc[4] = {};
    float m = -3.0e38f, l = 0.f;

    __syncthreads();                            // stage(0) landed (vmcnt drain)

    for (int kt = 0; kt < nt; kt++) {
      const int buf = kt & 1;
      if (kt + 1 < nt) stage(kt + 1, buf ^ 1);

      if (kt * 128 + v * 32 <= q0 + s * 32 + 31) {   // wave has unmasked work
        const char* KsB = LB + buf * 65536;
        const char* VsB = LB + 32768 + buf * 65536;

        // ---- S^T = K Q^T : keys [32v,32v+32), q-col = c31 ----
        f32x16 sacc = {};
        __builtin_amdgcn_s_setprio(1);
        #pragma unroll
        for (int ss = 0; ss < 8; ss++) {
          int row = v * 32 + c31;
          bf16x8 kf = *(const bf16x8*)(KsB + row * 256
                                       + ((ss * 32 + hi * 16) ^ ((row & 15) << 4)));
          sacc = __builtin_amdgcn_mfma_f32_32x32x16_bf16(kf, qf[ss], sacc, 0, 0, 0);
        }
        __builtin_amdgcn_s_setprio(0);

        // ---- per-q max over the wave's 32 keys (log2 domain) ----
        float t0[8];
        #pragma unroll
        for (int r = 0; r < 8; r++) t0[r] = fmaxf(sacc[r], sacc[r + 8]);
        #pragma unroll
        for (int d = 4; d > 0; d >>= 1)
          #pragma unroll
          for (int r = 0; r < 4; r++) if (r < d) t0[r] = fmaxf(t0[r], t0[r + d]);
        float mx = t0[0];
        i32x2 mm = __builtin_amdgcn_permlane32_swap(__float_as_int(mx), __float_as_int(mx),
                                                    false, false);
        mx = fmaxf(__int_as_float(mm.x), __int_as_float(mm.y));

        // ---- defer-max rescale (THR = 8/ln2 in log2 domain) ----
        if (__any(mx > m + 11.5416f)) {
          float mn = fmaxf(m, mx);
          float al = exp2r(m - mn);
          m = mn; l *= al;
          #pragma unroll
          for (int g = 0; g < 4; g++)
            #pragma unroll
            for (int r = 0; r < 16; r++) oacc[g][r] *= al;
        }

        // ---- exp2 + causal mask ----
        const int rel = qrow - kt * 128 - v * 32;     // keep key_local <= rel
        const bool maskT = (kt * 128 + v * 32 + 31) > (q0 + s * 32);
        #pragma unroll
        for (int r = 0; r < 16; r++) {
          float e = exp2r(sacc[r] - m);
          if (maskT) {
            int kl = (r & 3) + 8 * (r >> 2) + 4 * hi;
            e = (kl > rel) ? 0.f : e;
          }
          sacc[r] = e;
        }

        // ---- per-(hi,q) sum -> l ----
        float s0[8];
        #pragma unroll
        for (int r = 0; r < 8; r++) s0[r] = sacc[r] + sacc[r + 8];
        #pragma unroll
        for (int d = 4; d > 0; d >>= 1)
          #pragma unroll
          for (int r = 0; r < 4; r++) if (r < d) s0[r] = s0[r] + s0[r + d];
        l += s0[0];

        // ---- P^T B-fragments via cvt_pk + permlane32_swap (T12) ----
        bf16x8 pa[2];
        #pragma unroll
        for (int sg = 0; sg < 2; sg++) {
          int q0a = cvtpk(sacc[8 * sg + 0], sacc[8 * sg + 1]);
          int q1a = cvtpk(sacc[8 * sg + 2], sacc[8 * sg + 3]);
          int q0b = cvtpk(sacc[8 * sg + 4], sacc[8 * sg + 5]);
          int q1b = cvtpk(sacc[8 * sg + 6], sacc[8 * sg + 7]);
          i32x2 r0 = __builtin_amdgcn_permlane32_swap(q0a, q0b, false, false);
          i32x2 r1 = __builtin_amdgcn_permlane32_swap(q1a, q1b, false, false);
          union { int d[4]; bf16x8 vv; } u;
          u.d[0] = r0.x; u.d[1] = r1.x; u.d[2] = r0.y; u.d[3] = r1.y;
          pa[sg] = u.vv;
        }

        // ---- partial O^T += V^T P^T over keys [32v, 32v+32) ----
        __builtin_amdgcn_s_setprio(1);
        #pragma unroll
        for (int ks = 0; ks < 2; ks++)
          #pragma unroll
          for (int g = 0; g < 4; g++) {
            int row = g * 32 + c31;
            bf16x8 vf = *(const bf16x8*)(VsB + row * 256
                         + ((v * 64 + ks * 32 + hi * 16) ^ ((row & 15) << 4)));
            oacc[g] = __builtin_amdgcn_mfma_f32_32x32x16_bf16(vf, pa[ks], oacc[g], 0, 0, 0);
          }
        __builtin_amdgcn_s_setprio(0);
      }
      __syncthreads();   // staged loads landed; all waves done with buf
    }

    // ---- combine l across the hi pair (m already shared) ----
    i32x2 lr = __builtin_amdgcn_permlane32_swap(__float_as_int(l), __float_as_int(l),
                                                false, false);
    l = __int_as_float(lr.x) + __int_as_float(lr.y);

    // ---- 2-round merge of the 4 kv-quarter partials ----
    // round 1: v=1 -> region0, v=3 -> region1; v=0 folds r0, v=2 folds r1.
    // round 2: v=2 -> region0; v=0 folds r0, normalizes, writes O.
    auto publish = [&](int r) {
      float* Op = (float*)(LB + r * 65536) + s * 4096;
      #pragma unroll
      for (int g = 0; g < 4; g++)
        #pragma unroll
        for (int rr = 0; rr < 16; rr++) {
          int d = g * 32 + (rr & 3) + 8 * (rr >> 2) + 4 * hi;
          Op[d * 32 + c31] = oacc[g][rr];
        }
      if (hi == 0) {
        float* mm2 = (float*)(LB + 131072 + r * 1024) + (s * 32 + c31) * 2;
        mm2[0] = m; mm2[1] = l;
      }
    };
    auto fold = [&](int r) {
      const float* mm2 = (const float*)(LB + 131072 + r * 1024) + (s * 32 + c31) * 2;
      float lB = mm2[1];
      float mB = (lB > 0.f) ? mm2[0] : -3.0e38f;
      float ms = fmaxf(m, mB);
      float aA = exp2r(m - ms), aB = exp2r(mB - ms);
      const float* Op = (const float*)(LB + r * 65536) + s * 4096;
      #pragma unroll
      for (int g = 0; g < 4; g++)
        #pragma unroll
        for (int rr = 0; rr < 16; rr++) {
          int d = g * 32 + (rr & 3) + 8 * (rr >> 2) + 4 * hi;
          oacc[g][rr] = oacc[g][rr] * aA + Op[d * 32 + c31] * aB;
        }
      m = ms; l = l * aA + lB * aB;
    };

    if (v & 1) publish(v >> 1);
    __syncthreads();
    if (!(v & 1)) fold(v >> 1);
    __syncthreads();                 // v0 done reading r0 before v2 overwrites
    if (v == 2) publish(0);
    __syncthreads();
    if (v == 0) {
      fold(0);
      float inv = 1.0f / l;
      #pragma unroll
      for (int g = 0; g < 4; g++)
        #pragma unroll
        for (int tt = 0; tt < 4; tt++) {
          u32x2 pk;
          pk.x = (unsigned)cvtpk(oacc[g][4 * tt + 0] * inv, oacc[g][4 * tt + 1] * inv);
          pk.y = (unsigned)cvtpk(oacc[g][4 * tt + 2] * inv, oacc[g][4 * tt + 3] * inv);
          *(u32x2*)(O + (size_t)qrow * DM + h * HD + g * 32 + tt * 8 + hi * 4) = pk;
        }
    }
  }
}

extern "C" void kernel_launch(void* const* d_in, const int* in_sizes, int n_in,
                              void* d_out, int out_size, void* d_ws, size_t ws_size,
                              hipStream_t stream) {
  const float* x  = (const float*)d_in[0];
  const float* wq = (const float*)d_in[1];
  const float* wk = (const float*)d_in[2];
  const float* wv = (const float*)d_in[3];
  const float* wo = (const float*)d_in[4];
  float* out = (float*)d_out;

  const size_t SQDMs = (size_t)SEQ * DM;   // 8M elements
  short* Qb   = (short*)d_ws;
  short* Kb   = Qb + SQDMs;
  short* VTb  = Kb + SQDMs;
  short* Cb   = VTb + SQDMs;
  short* xbf  = Cb + SQDMs;
  short* wbuf = xbf + SQDMs;
  float2* tab = (float2*)(wbuf + (size_t)DM * DM);

  rope_tables_kernel<<<SEQ * 64 / 256, 256, 0, stream>>>(tab);
  f32_to_bf16_kernel<<<2048, 256, 0, stream>>>(x, xbf, (int)(SQDMs / 4));

  dim3 g(SEQ / 128, DM / 128);
  f32_to_bf16_kernel<<<2048, 256, 0, stream>>>(wq, wbuf, DM * DM / 4);
  gemm_rope_kernel<1><<<g, 256, 0, stream>>>(xbf, wbuf, Qb, tab);
  f32_to_bf16_kernel<<<2048, 256, 0, stream>>>(wk, wbuf, DM * DM / 4);
  gemm_rope_kernel<0><<<g, 256, 0, stream>>>(xbf, wbuf, Kb, tab);
  f32_to_bf16_kernel<<<2048, 256, 0, stream>>>(wv, wbuf, DM * DM / 4);
  gemm_async_kernel<2><<<g, 256, 0, stream>>>(xbf, wbuf, VTb, SEQ, DM, DM);

  flash_attn5_kernel<<<256, 1024, 0, stream>>>(Qb, Kb, VTb, Cb);

  f32_to_bf16_kernel<<<2048, 256, 0, stream>>>(wo, wbuf, DM * DM / 4);
  gemm_async_kernel<0><<<g, 256, 0, stream>>>(Cb, wbuf, out, SEQ, DM, DM);
}

// Round 7
// 461.342 us; speedup vs baseline: 1.0038x; 1.0038x over previous
//
#include <hip/hip_runtime.h>
#include <hip/hip_bf16.h>
#include <stdint.h>

#define SEQ 4096
#define DM 2048
#define NH 16
#define HD 128

typedef __attribute__((ext_vector_type(4)))  float f32x4;
typedef __attribute__((ext_vector_type(16))) float f32x16;
typedef __attribute__((ext_vector_type(8)))  short bf16x8;
typedef __attribute__((ext_vector_type(4)))  float float4_t;
typedef __attribute__((ext_vector_type(4)))  short s16x4;
typedef __attribute__((ext_vector_type(2)))  int   i32x2;
typedef __attribute__((ext_vector_type(2)))  unsigned u32x2;

__device__ __forceinline__ short f2bf(float f) {
  union { float f; unsigned u; } c; c.f = f;
  unsigned u = c.u;
  u += 0x7FFFu + ((u >> 16) & 1u);   // RNE
  return (short)(u >> 16);
}

__device__ __forceinline__ int cvtpk(float lo, float hi) {
  int r;
  asm("v_cvt_pk_bf16_f32 %0, %1, %2" : "=v"(r) : "v"(lo), "v"(hi));
  return r;
}

__device__ __forceinline__ float exp2r(float x) {   // raw v_exp_f32
  return __builtin_amdgcn_exp2f(x);
}

__device__ __forceinline__ void async16(const void* g, void* l) {
  __builtin_amdgcn_global_load_lds((const __attribute__((address_space(1))) void*)g,
                                   (__attribute__((address_space(3))) void*)l, 16, 0, 0);
}

__global__ __launch_bounds__(256) void rope_tables_kernel(float2* __restrict__ tab) {
  int idx = blockIdx.x * 256 + threadIdx.x;  // SEQ*64
  int s = idx >> 6, j = idx & 63;
  float invf = expf(-(float)j * (9.210340371976184f / 64.0f)); // 10000^(-j/64)
  float ang = (float)s * invf;
  tab[idx] = make_float2(cosf(ang), sinf(ang));
}

__global__ __launch_bounds__(256) void f32_to_bf16_kernel(const float* __restrict__ in,
                                                          short* __restrict__ out, int n4) {
  int stride = gridDim.x * 256;
  for (int i = blockIdx.x * 256 + threadIdx.x; i < n4; i += stride) {
    float4_t v = ((const float4_t*)in)[i];
    s16x4 r;
    #pragma unroll
    for (int u = 0; u < 4; u++) r[u] = f2bf(v[u]);
    ((s16x4*)out)[i] = r;
  }
}

// ---------------- GEMM: bf16 in, global_load_lds staging, BK=64 ------------
// C[M][N] = A[M][K] * B[N][K]^T. OUT_MODE: 0 f32, 2 bf16 transposed.
template<int OUT_MODE>
__global__ __launch_bounds__(256) void gemm_async_kernel(
    const short* __restrict__ A, const short* __restrict__ B,
    void* __restrict__ Cp, int M, int N, int K) {
  __shared__ short As[128 * 64];
  __shared__ short Bs[128 * 64];
  const int t = threadIdx.x, lane = t & 63, w = t >> 6;
  const int wr = w >> 1, wc = w & 1;
  const size_t Mbase = (size_t)blockIdx.x * 128;
  const size_t Nbase = (size_t)blockIdx.y * 128;
  f32x4 acc[4][4] = {};

  for (int k0 = 0; k0 < K; k0 += 64) {
    __syncthreads();
    #pragma unroll
    for (int c = 0; c < 4; c++) {
      int ob = w * 4096 + c * 1024;           // uniform per wave
      int o = ob + lane * 16;
      int row = o >> 7;
      int cb = (o & 127) ^ ((row & 7) << 4);
      async16((const char*)A + ((Mbase + row) * (size_t)K + k0) * 2 + cb, (char*)As + ob);
      async16((const char*)B + ((Nbase + row) * (size_t)K + k0) * 2 + cb, (char*)Bs + ob);
    }
    __syncthreads();

    bf16x8 a[2][4], b[2][4];
    #pragma unroll
    for (int ks = 0; ks < 2; ks++) {
      #pragma unroll
      for (int m = 0; m < 4; m++) {
        int row = wr * 64 + m * 16 + (lane & 15);
        int chunk = ks * 64 + (lane >> 4) * 16;
        a[ks][m] = *(const bf16x8*)((const char*)As + row * 128 + (chunk ^ ((row & 7) << 4)));
      }
      #pragma unroll
      for (int n = 0; n < 4; n++) {
        int row = wc * 64 + n * 16 + (lane & 15);
        int chunk = ks * 64 + (lane >> 4) * 16;
        b[ks][n] = *(const bf16x8*)((const char*)Bs + row * 128 + (chunk ^ ((row & 7) << 4)));
      }
    }
    #pragma unroll
    for (int ks = 0; ks < 2; ks++)
      #pragma unroll
      for (int m = 0; m < 4; m++)
        #pragma unroll
        for (int n = 0; n < 4; n++)
          acc[m][n] = __builtin_amdgcn_mfma_f32_16x16x32_bf16(a[ks][m], b[ks][n], acc[m][n], 0, 0, 0);
  }

  #pragma unroll
  for (int m = 0; m < 4; m++)
    #pragma unroll
    for (int n = 0; n < 4; n++)
      #pragma unroll
      for (int j = 0; j < 4; j++) {
        size_t row = Mbase + wr * 64 + m * 16 + (lane >> 4) * 4 + j;
        size_t col = Nbase + wc * 64 + n * 16 + (lane & 15);
        float v = acc[m][n][j];
        if (OUT_MODE == 0) ((float*)Cp)[row * N + col] = v;
        else               ((short*)Cp)[col * (size_t)M + row] = f2bf(v);
      }
}

// ---------------- GEMM + fused RoPE epilogue (Q/K projections) -------------
// Wave tiling 4x1: wave w owns rows w*32..w*32+31, all 128 cols (one head).
// IS_Q folds log2e/sqrt(HD) into Q so attention works in exp2 domain.
template<int IS_Q>
__global__ __launch_bounds__(256) void gemm_rope_kernel(
    const short* __restrict__ A, const short* __restrict__ B,
    short* __restrict__ C, const float2* __restrict__ tab) {
  __shared__ short As[128 * 64];
  __shared__ short Bs[128 * 64];
  const int t = threadIdx.x, lane = t & 63, w = t >> 6;
  const size_t Mbase = (size_t)blockIdx.x * 128;
  const size_t Nbase = (size_t)blockIdx.y * 128;
  const int K = DM;
  f32x4 acc[2][8] = {};

  for (int k0 = 0; k0 < K; k0 += 64) {
    __syncthreads();
    #pragma unroll
    for (int c = 0; c < 4; c++) {
      int ob = w * 4096 + c * 1024;
      int o = ob + lane * 16;
      int row = o >> 7;
      int cb = (o & 127) ^ ((row & 7) << 4);
      async16((const char*)A + ((Mbase + row) * (size_t)K + k0) * 2 + cb, (char*)As + ob);
      async16((const char*)B + ((Nbase + row) * (size_t)K + k0) * 2 + cb, (char*)Bs + ob);
    }
    __syncthreads();

    bf16x8 a[2][2], b[2][8];
    #pragma unroll
    for (int ks = 0; ks < 2; ks++) {
      #pragma unroll
      for (int m = 0; m < 2; m++) {
        int row = w * 32 + m * 16 + (lane & 15);
        int chunk = ks * 64 + (lane >> 4) * 16;
        a[ks][m] = *(const bf16x8*)((const char*)As + row * 128 + (chunk ^ ((row & 7) << 4)));
      }
      #pragma unroll
      for (int n = 0; n < 8; n++) {
        int row = n * 16 + (lane & 15);
        int chunk = ks * 64 + (lane >> 4) * 16;
        b[ks][n] = *(const bf16x8*)((const char*)Bs + row * 128 + (chunk ^ ((row & 7) << 4)));
      }
    }
    #pragma unroll
    for (int ks = 0; ks < 2; ks++)
      #pragma unroll
      for (int m = 0; m < 2; m++)
        #pragma unroll
        for (int n = 0; n < 8; n++)
          acc[m][n] = __builtin_amdgcn_mfma_f32_16x16x32_bf16(a[ks][m], b[ks][n], acc[m][n], 0, 0, 0);
  }

  // Q: scale = log2(e)/sqrt(128) so attention uses exp2 directly.
  const float SC = IS_Q ? 0.12751746f : 1.0f;
  #pragma unroll
  for (int m = 0; m < 2; m++)
    #pragma unroll
    for (int n = 0; n < 4; n++)
      #pragma unroll
      for (int j = 0; j < 4; j++) {
        int row = (int)Mbase + w * 32 + m * 16 + (lane >> 4) * 4 + j;   // seq pos
        int dj = n * 16 + (lane & 15);                                  // 0..63
        float2 cs = tab[row * 64 + dj];
        float cc = cs.x * SC, ss = cs.y * SC;
        float r1 = acc[m][n][j], r2 = acc[m][n + 4][j];
        C[(size_t)row * DM + Nbase + dj]      = f2bf(r1 * cc - r2 * ss);
        C[(size_t)row * DM + Nbase + dj + 64] = f2bf(r2 * cc + r1 * ss);
      }
}

// ---------------- flash attention v6: 16 waves, QBLK=128, kv-quarters ------
// Identical structure to v5 (r6) EXCEPT __launch_bounds__(1024, 1):
// r6's (1024,4) was treated as 4 blocks/CU -> VGPR capped at 64 -> ~380MB of
// scratch spill traffic (FETCH 402MB vs 24.7 ideal). (1024,1) -> cap 128,
// the same VGPR count the 8-wave r5 kernel fit in with zero spill.
__global__ __launch_bounds__(1024, 1) void flash_attn6_kernel(
    const short* __restrict__ Q, const short* __restrict__ K,
    const short* __restrict__ VT, short* __restrict__ O) {
  // LDS: buf b: K at b*65536 (32KB, 128 rows x 256B), V^T at 32768+b*65536
  // (32KB, 128 d-rows x 256B). Merge overlay: region r = [r*65536, +64KB)
  // as [4 strip][128 d][32 q] fp32; ml slots at 131072 + r*1024.
  __shared__ __align__(16) char LB[133120];
  const int t = threadIdx.x, lane = t & 63, w = t >> 6;   // w: 0..15
  const int hi = lane >> 5, c31 = lane & 31;
  const int s = w & 3, v = w >> 2;                // strip, kv-quarter
  const int id = blockIdx.x;                      // 0..255
  const int h  = (id & 7) * 2 + ((id >> 3) & 1);  // 2 heads per XCD
  const int pr = id >> 4;                         // 0..15

  auto stage = [&](int kt, int buf) {
    #pragma unroll
    for (int it = 0; it < 2; it++) {
      const int ob = w * 2048 + it * 1024;        // wave-uniform LDS byte base
      const int o  = ob + lane * 16;
      const int row = o >> 8;
      const int xs = (o & 255) ^ ((row & 15) << 4);
      async16((const char*)K + ((size_t)(kt * 128 + row) * DM + h * HD) * 2 + xs,
              LB + buf * 65536 + ob);
      async16((const char*)VT + ((size_t)(h * HD + row) * SEQ + (size_t)kt * 128) * 2 + xs,
              LB + 32768 + buf * 65536 + ob);
    }
  };

  for (int rep = 0; rep < 2; rep++) {
    const int qt = rep ? (31 - pr) : pr;        // 128-row q-tile; single cover
    const int q0 = qt * 128;
    const int nt = qt + 1;
    const int qrow = q0 + s * 32 + c31;         // this lane's q-row

    __syncthreads();                            // prior rep's merge reads done
    stage(0, 0);

    // Q fragments (B-operand): lane holds Q[qrow][16ss+8hi .. +7]
    bf16x8 qf[8];
    #pragma unroll
    for (int ss = 0; ss < 8; ss++)
      qf[ss] = *(const bf16x8*)(Q + (size_t)qrow * DM + h * HD + ss * 16 + hi * 8);

    f32x16 oacc[4] = {};
    float m = -3.0e38f, l = 0.f;

    __syncthreads();                            // stage(0) landed (vmcnt drain)

    for (int kt = 0; kt < nt; kt++) {
      const int buf = kt & 1;
      if (kt + 1 < nt) stage(kt + 1, buf ^ 1);

      if (kt * 128 + v * 32 <= q0 + s * 32 + 31) {   // wave has unmasked work
        const char* KsB = LB + buf * 65536;
        const char* VsB = LB + 32768 + buf * 65536;

        // ---- S^T = K Q^T : keys [32v,32v+32), q-col = c31 ----
        f32x16 sacc = {};
        __builtin_amdgcn_s_setprio(1);
        #pragma unroll
        for (int ss = 0; ss < 8; ss++) {
          int row = v * 32 + c31;
          bf16x8 kf = *(const bf16x8*)(KsB + row * 256
                                       + ((ss * 32 + hi * 16) ^ ((row & 15) << 4)));
          sacc = __builtin_amdgcn_mfma_f32_32x32x16_bf16(kf, qf[ss], sacc, 0, 0, 0);
        }
        __builtin_amdgcn_s_setprio(0);

        // ---- per-q max over the wave's 32 keys (log2 domain) ----
        float t0[8];
        #pragma unroll
        for (int r = 0; r < 8; r++) t0[r] = fmaxf(sacc[r], sacc[r + 8]);
        #pragma unroll
        for (int d = 4; d > 0; d >>= 1)
          #pragma unroll
          for (int r = 0; r < 4; r++) if (r < d) t0[r] = fmaxf(t0[r], t0[r + d]);
        float mx = t0[0];
        i32x2 mm = __builtin_amdgcn_permlane32_swap(__float_as_int(mx), __float_as_int(mx),
                                                    false, false);
        mx = fmaxf(__int_as_float(mm.x), __int_as_float(mm.y));

        // ---- defer-max rescale (THR = 8/ln2 in log2 domain) ----
        if (__any(mx > m + 11.5416f)) {
          float mn = fmaxf(m, mx);
          float al = exp2r(m - mn);
          m = mn; l *= al;
          #pragma unroll
          for (int g = 0; g < 4; g++)
            #pragma unroll
            for (int r = 0; r < 16; r++) oacc[g][r] *= al;
        }

        // ---- exp2 + causal mask ----
        const int rel = qrow - kt * 128 - v * 32;     // keep key_local <= rel
        const bool maskT = (kt * 128 + v * 32 + 31) > (q0 + s * 32);
        #pragma unroll
        for (int r = 0; r < 16; r++) {
          float e = exp2r(sacc[r] - m);
          if (maskT) {
            int kl = (r & 3) + 8 * (r >> 2) + 4 * hi;
            e = (kl > rel) ? 0.f : e;
          }
          sacc[r] = e;
        }

        // ---- per-(hi,q) sum -> l ----
        float s0[8];
        #pragma unroll
        for (int r = 0; r < 8; r++) s0[r] = sacc[r] + sacc[r + 8];
        #pragma unroll
        for (int d = 4; d > 0; d >>= 1)
          #pragma unroll
          for (int r = 0; r < 4; r++) if (r < d) s0[r] = s0[r] + s0[r + d];
        l += s0[0];

        // ---- P^T B-fragments via cvt_pk + permlane32_swap (T12) ----
        bf16x8 pa[2];
        #pragma unroll
        for (int sg = 0; sg < 2; sg++) {
          int q0a = cvtpk(sacc[8 * sg + 0], sacc[8 * sg + 1]);
          int q1a = cvtpk(sacc[8 * sg + 2], sacc[8 * sg + 3]);
          int q0b = cvtpk(sacc[8 * sg + 4], sacc[8 * sg + 5]);
          int q1b = cvtpk(sacc[8 * sg + 6], sacc[8 * sg + 7]);
          i32x2 r0 = __builtin_amdgcn_permlane32_swap(q0a, q0b, false, false);
          i32x2 r1 = __builtin_amdgcn_permlane32_swap(q1a, q1b, false, false);
          union { int d[4]; bf16x8 vv; } u;
          u.d[0] = r0.x; u.d[1] = r1.x; u.d[2] = r0.y; u.d[3] = r1.y;
          pa[sg] = u.vv;
        }

        // ---- partial O^T += V^T P^T over keys [32v, 32v+32) ----
        __builtin_amdgcn_s_setprio(1);
        #pragma unroll
        for (int ks = 0; ks < 2; ks++)
          #pragma unroll
          for (int g = 0; g < 4; g++) {
            int row = g * 32 + c31;
            bf16x8 vf = *(const bf16x8*)(VsB + row * 256
                         + ((v * 64 + ks * 32 + hi * 16) ^ ((row & 15) << 4)));
            oacc[g] = __builtin_amdgcn_mfma_f32_32x32x16_bf16(vf, pa[ks], oacc[g], 0, 0, 0);
          }
        __builtin_amdgcn_s_setprio(0);
      }
      __syncthreads();   // staged loads landed; all waves done with buf
    }

    // ---- combine l across the hi pair (m already shared) ----
    i32x2 lr = __builtin_amdgcn_permlane32_swap(__float_as_int(l), __float_as_int(l),
                                                false, false);
    l = __int_as_float(lr.x) + __int_as_float(lr.y);

    // ---- 2-round merge of the 4 kv-quarter partials ----
    // round 1: v=1 -> region0, v=3 -> region1; v=0 folds r0, v=2 folds r1.
    // round 2: v=2 -> region0; v=0 folds r0, normalizes, writes O.
    auto publish = [&](int r) {
      float* Op = (float*)(LB + r * 65536) + s * 4096;
      #pragma unroll
      for (int g = 0; g < 4; g++)
        #pragma unroll
        for (int rr = 0; rr < 16; rr++) {
          int d = g * 32 + (rr & 3) + 8 * (rr >> 2) + 4 * hi;
          Op[d * 32 + c31] = oacc[g][rr];
        }
      if (hi == 0) {
        float* mm2 = (float*)(LB + 131072 + r * 1024) + (s * 32 + c31) * 2;
        mm2[0] = m; mm2[1] = l;
      }
    };
    auto fold = [&](int r) {
      const float* mm2 = (const float*)(LB + 131072 + r * 1024) + (s * 32 + c31) * 2;
      float lB = mm2[1];
      float mB = (lB > 0.f) ? mm2[0] : -3.0e38f;
      float ms = fmaxf(m, mB);
      float aA = exp2r(m - ms), aB = exp2r(mB - ms);
      const float* Op = (const float*)(LB + r * 65536) + s * 4096;
      #pragma unroll
      for (int g = 0; g < 4; g++)
        #pragma unroll
        for (int rr = 0; rr < 16; rr++) {
          int d = g * 32 + (rr & 3) + 8 * (rr >> 2) + 4 * hi;
          oacc[g][rr] = oacc[g][rr] * aA + Op[d * 32 + c31] * aB;
        }
      m = ms; l = l * aA + lB * aB;
    };

    if (v & 1) publish(v >> 1);
    __syncthreads();
    if (!(v & 1)) fold(v >> 1);
    __syncthreads();                 // v0 done reading r0 before v2 overwrites
    if (v == 2) publish(0);
    __syncthreads();
    if (v == 0) {
      fold(0);
      float inv = 1.0f / l;
      #pragma unroll
      for (int g = 0; g < 4; g++)
        #pragma unroll
        for (int tt = 0; tt < 4; tt++) {
          u32x2 pk;
          pk.x = (unsigned)cvtpk(oacc[g][4 * tt + 0] * inv, oacc[g][4 * tt + 1] * inv);
          pk.y = (unsigned)cvtpk(oacc[g][4 * tt + 2] * inv, oacc[g][4 * tt + 3] * inv);
          *(u32x2*)(O + (size_t)qrow * DM + h * HD + g * 32 + tt * 8 + hi * 4) = pk;
        }
    }
  }
}

extern "C" void kernel_launch(void* const* d_in, const int* in_sizes, int n_in,
                              void* d_out, int out_size, void* d_ws, size_t ws_size,
                              hipStream_t stream) {
  const float* x  = (const float*)d_in[0];
  const float* wq = (const float*)d_in[1];
  const float* wk = (const float*)d_in[2];
  const float* wv = (const float*)d_in[3];
  const float* wo = (const float*)d_in[4];
  float* out = (float*)d_out;

  const size_t SQDMs = (size_t)SEQ * DM;   // 8M elements
  short* Qb   = (short*)d_ws;
  short* Kb   = Qb + SQDMs;
  short* VTb  = Kb + SQDMs;
  short* Cb   = VTb + SQDMs;
  short* xbf  = Cb + SQDMs;
  short* wbuf = xbf + SQDMs;
  float2* tab = (float2*)(wbuf + (size_t)DM * DM);

  rope_tables_kernel<<<SEQ * 64 / 256, 256, 0, stream>>>(tab);
  f32_to_bf16_kernel<<<2048, 256, 0, stream>>>(x, xbf, (int)(SQDMs / 4));

  dim3 g(SEQ / 128, DM / 128);
  f32_to_bf16_kernel<<<2048, 256, 0, stream>>>(wq, wbuf, DM * DM / 4);
  gemm_rope_kernel<1><<<g, 256, 0, stream>>>(xbf, wbuf, Qb, tab);
  f32_to_bf16_kernel<<<2048, 256, 0, stream>>>(wk, wbuf, DM * DM / 4);
  gemm_rope_kernel<0><<<g, 256, 0, stream>>>(xbf, wbuf, Kb, tab);
  f32_to_bf16_kernel<<<2048, 256, 0, stream>>>(wv, wbuf, DM * DM / 4);
  gemm_async_kernel<2><<<g, 256, 0, stream>>>(xbf, wbuf, VTb, SEQ, DM, DM);

  flash_attn6_kernel<<<256, 1024, 0, stream>>>(Qb, Kb, VTb, Cb);

  f32_to_bf16_kernel<<<2048, 256, 0, stream>>>(wo, wbuf, DM * DM / 4);
  gemm_async_kernel<0><<<g, 256, 0, stream>>>(Cb, wbuf, out, SEQ, DM, DM);
}

// Round 8
// 460.195 us; speedup vs baseline: 1.0063x; 1.0025x over previous
//
#include <hip/hip_runtime.h>
#include <hip/hip_bf16.h>
#include <stdint.h>

#define SEQ 4096
#define DM 2048
#define NH 16
#define HD 128

typedef __attribute__((ext_vector_type(4)))  float f32x4;
typedef __attribute__((ext_vector_type(16))) float f32x16;
typedef __attribute__((ext_vector_type(8)))  short bf16x8;
typedef __attribute__((ext_vector_type(4)))  float float4_t;
typedef __attribute__((ext_vector_type(4)))  short s16x4;
typedef __attribute__((ext_vector_type(2)))  int   i32x2;
typedef __attribute__((ext_vector_type(2)))  unsigned u32x2;

__device__ __forceinline__ short f2bf(float f) {
  union { float f; unsigned u; } c; c.f = f;
  unsigned u = c.u;
  u += 0x7FFFu + ((u >> 16) & 1u);   // RNE
  return (short)(u >> 16);
}

__device__ __forceinline__ int cvtpk(float lo, float hi) {
  int r;
  asm("v_cvt_pk_bf16_f32 %0, %1, %2" : "=v"(r) : "v"(lo), "v"(hi));
  return r;
}

__device__ __forceinline__ float exp2r(float x) {   // raw v_exp_f32
  return __builtin_amdgcn_exp2f(x);
}

__device__ __forceinline__ void async16(const void* g, void* l) {
  __builtin_amdgcn_global_load_lds((const __attribute__((address_space(1))) void*)g,
                                   (__attribute__((address_space(3))) void*)l, 16, 0, 0);
}

__global__ __launch_bounds__(256) void rope_tables_kernel(float2* __restrict__ tab) {
  int idx = blockIdx.x * 256 + threadIdx.x;  // SEQ*64
  int s = idx >> 6, j = idx & 63;
  float invf = expf(-(float)j * (9.210340371976184f / 64.0f)); // 10000^(-j/64)
  float ang = (float)s * invf;
  tab[idx] = make_float2(cosf(ang), sinf(ang));
}

__global__ __launch_bounds__(256) void f32_to_bf16_kernel(const float* __restrict__ in,
                                                          short* __restrict__ out, int n4) {
  int stride = gridDim.x * 256;
  for (int i = blockIdx.x * 256 + threadIdx.x; i < n4; i += stride) {
    float4_t v = ((const float4_t*)in)[i];
    s16x4 r;
    #pragma unroll
    for (int u = 0; u < 4; u++) r[u] = f2bf(v[u]);
    ((s16x4*)out)[i] = r;
  }
}

// ---------------- GEMM: bf16 in, global_load_lds staging, BK=64 ------------
// C[M][N] = A[M][K] * B[N][K]^T. OUT_MODE: 0 f32, 2 bf16 transposed.
template<int OUT_MODE>
__global__ __launch_bounds__(256) void gemm_async_kernel(
    const short* __restrict__ A, const short* __restrict__ B,
    void* __restrict__ Cp, int M, int N, int K) {
  __shared__ short As[128 * 64];
  __shared__ short Bs[128 * 64];
  const int t = threadIdx.x, lane = t & 63, w = t >> 6;
  const int wr = w >> 1, wc = w & 1;
  const size_t Mbase = (size_t)blockIdx.x * 128;
  const size_t Nbase = (size_t)blockIdx.y * 128;
  f32x4 acc[4][4] = {};

  for (int k0 = 0; k0 < K; k0 += 64) {
    __syncthreads();
    #pragma unroll
    for (int c = 0; c < 4; c++) {
      int ob = w * 4096 + c * 1024;           // uniform per wave
      int o = ob + lane * 16;
      int row = o >> 7;
      int cb = (o & 127) ^ ((row & 7) << 4);
      async16((const char*)A + ((Mbase + row) * (size_t)K + k0) * 2 + cb, (char*)As + ob);
      async16((const char*)B + ((Nbase + row) * (size_t)K + k0) * 2 + cb, (char*)Bs + ob);
    }
    __syncthreads();

    bf16x8 a[2][4], b[2][4];
    #pragma unroll
    for (int ks = 0; ks < 2; ks++) {
      #pragma unroll
      for (int m = 0; m < 4; m++) {
        int row = wr * 64 + m * 16 + (lane & 15);
        int chunk = ks * 64 + (lane >> 4) * 16;
        a[ks][m] = *(const bf16x8*)((const char*)As + row * 128 + (chunk ^ ((row & 7) << 4)));
      }
      #pragma unroll
      for (int n = 0; n < 4; n++) {
        int row = wc * 64 + n * 16 + (lane & 15);
        int chunk = ks * 64 + (lane >> 4) * 16;
        b[ks][n] = *(const bf16x8*)((const char*)Bs + row * 128 + (chunk ^ ((row & 7) << 4)));
      }
    }
    #pragma unroll
    for (int ks = 0; ks < 2; ks++)
      #pragma unroll
      for (int m = 0; m < 4; m++)
        #pragma unroll
        for (int n = 0; n < 4; n++)
          acc[m][n] = __builtin_amdgcn_mfma_f32_16x16x32_bf16(a[ks][m], b[ks][n], acc[m][n], 0, 0, 0);
  }

  #pragma unroll
  for (int m = 0; m < 4; m++)
    #pragma unroll
    for (int n = 0; n < 4; n++)
      #pragma unroll
      for (int j = 0; j < 4; j++) {
        size_t row = Mbase + wr * 64 + m * 16 + (lane >> 4) * 4 + j;
        size_t col = Nbase + wc * 64 + n * 16 + (lane & 15);
        float v = acc[m][n][j];
        if (OUT_MODE == 0) ((float*)Cp)[row * N + col] = v;
        else               ((short*)Cp)[col * (size_t)M + row] = f2bf(v);
      }
}

// ---------------- GEMM + fused RoPE epilogue (Q/K projections) -------------
// Wave tiling 4x1: wave w owns rows w*32..w*32+31, all 128 cols (one head).
// IS_Q folds log2e/sqrt(HD) into Q so attention works in exp2 domain.
template<int IS_Q>
__global__ __launch_bounds__(256) void gemm_rope_kernel(
    const short* __restrict__ A, const short* __restrict__ B,
    short* __restrict__ C, const float2* __restrict__ tab) {
  __shared__ short As[128 * 64];
  __shared__ short Bs[128 * 64];
  const int t = threadIdx.x, lane = t & 63, w = t >> 6;
  const size_t Mbase = (size_t)blockIdx.x * 128;
  const size_t Nbase = (size_t)blockIdx.y * 128;
  const int K = DM;
  f32x4 acc[2][8] = {};

  for (int k0 = 0; k0 < K; k0 += 64) {
    __syncthreads();
    #pragma unroll
    for (int c = 0; c < 4; c++) {
      int ob = w * 4096 + c * 1024;
      int o = ob + lane * 16;
      int row = o >> 7;
      int cb = (o & 127) ^ ((row & 7) << 4);
      async16((const char*)A + ((Mbase + row) * (size_t)K + k0) * 2 + cb, (char*)As + ob);
      async16((const char*)B + ((Nbase + row) * (size_t)K + k0) * 2 + cb, (char*)Bs + ob);
    }
    __syncthreads();

    bf16x8 a[2][2], b[2][8];
    #pragma unroll
    for (int ks = 0; ks < 2; ks++) {
      #pragma unroll
      for (int m = 0; m < 2; m++) {
        int row = w * 32 + m * 16 + (lane & 15);
        int chunk = ks * 64 + (lane >> 4) * 16;
        a[ks][m] = *(const bf16x8*)((const char*)As + row * 128 + (chunk ^ ((row & 7) << 4)));
      }
      #pragma unroll
      for (int n = 0; n < 8; n++) {
        int row = n * 16 + (lane & 15);
        int chunk = ks * 64 + (lane >> 4) * 16;
        b[ks][n] = *(const bf16x8*)((const char*)Bs + row * 128 + (chunk ^ ((row & 7) << 4)));
      }
    }
    #pragma unroll
    for (int ks = 0; ks < 2; ks++)
      #pragma unroll
      for (int m = 0; m < 2; m++)
        #pragma unroll
        for (int n = 0; n < 8; n++)
          acc[m][n] = __builtin_amdgcn_mfma_f32_16x16x32_bf16(a[ks][m], b[ks][n], acc[m][n], 0, 0, 0);
  }

  // Q: scale = log2(e)/sqrt(128) so attention uses exp2 directly.
  const float SC = IS_Q ? 0.12751746f : 1.0f;
  #pragma unroll
  for (int m = 0; m < 2; m++)
    #pragma unroll
    for (int n = 0; n < 4; n++)
      #pragma unroll
      for (int j = 0; j < 4; j++) {
        int row = (int)Mbase + w * 32 + m * 16 + (lane >> 4) * 4 + j;   // seq pos
        int dj = n * 16 + (lane & 15);                                  // 0..63
        float2 cs = tab[row * 64 + dj];
        float cc = cs.x * SC, ss = cs.y * SC;
        float r1 = acc[m][n][j], r2 = acc[m][n + 4][j];
        C[(size_t)row * DM + Nbase + dj]      = f2bf(r1 * cc - r2 * ss);
        C[(size_t)row * DM + Nbase + dj + 64] = f2bf(r2 * cc + r1 * ss);
      }
}

// ---------------- flash attention v7: 16 waves, QBLK=128, kv-quarters ------
// Byte-identical math to v5/v6. Register-budget fix attempt #3:
// direct LLVM attribute amdgpu_waves_per_eu(4,4) -> allocator targets exactly
// 4 waves/EU -> VGPR cap 128 (the live set fits in 128, proven r5).
// r6 (1024,4) and r7 (1024,1) both produced VGPR=64 + ~400MB spill traffic:
// HIP's launch_bounds 2nd arg is not reaching the backend for 1024-thr blocks.
__global__ __launch_bounds__(1024)
__attribute__((amdgpu_waves_per_eu(4, 4)))
void flash_attn7_kernel(
    const short* __restrict__ Q, const short* __restrict__ K,
    const short* __restrict__ VT, short* __restrict__ O) {
  // LDS: buf b: K at b*65536 (32KB, 128 rows x 256B), V^T at 32768+b*65536
  // (32KB, 128 d-rows x 256B). Merge overlay: region r = [r*65536, +64KB)
  // as [4 strip][128 d][32 q] fp32; ml slots at 131072 + r*1024.
  __shared__ __align__(16) char LB[133120];
  const int t = threadIdx.x, lane = t & 63, w = t >> 6;   // w: 0..15
  const int hi = lane >> 5, c31 = lane & 31;
  const int s = w & 3, v = w >> 2;                // strip, kv-quarter
  const int id = blockIdx.x;                      // 0..255
  const int h  = (id & 7) * 2 + ((id >> 3) & 1);  // 2 heads per XCD
  const int pr = id >> 4;                         // 0..15

  auto stage = [&](int kt, int buf) {
    #pragma unroll
    for (int it = 0; it < 2; it++) {
      const int ob = w * 2048 + it * 1024;        // wave-uniform LDS byte base
      const int o  = ob + lane * 16;
      const int row = o >> 8;
      const int xs = (o & 255) ^ ((row & 15) << 4);
      async16((const char*)K + ((size_t)(kt * 128 + row) * DM + h * HD) * 2 + xs,
              LB + buf * 65536 + ob);
      async16((const char*)VT + ((size_t)(h * HD + row) * SEQ + (size_t)kt * 128) * 2 + xs,
              LB + 32768 + buf * 65536 + ob);
    }
  };

  for (int rep = 0; rep < 2; rep++) {
    const int qt = rep ? (31 - pr) : pr;        // 128-row q-tile; single cover
    const int q0 = qt * 128;
    const int nt = qt + 1;
    const int qrow = q0 + s * 32 + c31;         // this lane's q-row

    __syncthreads();                            // prior rep's merge reads done
    stage(0, 0);

    // Q fragments (B-operand): lane holds Q[qrow][16ss+8hi .. +7]
    bf16x8 qf[8];
    #pragma unroll
    for (int ss = 0; ss < 8; ss++)
      qf[ss] = *(const bf16x8*)(Q + (size_t)qrow * DM + h * HD + ss * 16 + hi * 8);

    f32x16 oacc[4] = {};
    float m = -3.0e38f, l = 0.f;

    __syncthreads();                            // stage(0) landed (vmcnt drain)

    for (int kt = 0; kt < nt; kt++) {
      const int buf = kt & 1;
      if (kt + 1 < nt) stage(kt + 1, buf ^ 1);

      if (kt * 128 + v * 32 <= q0 + s * 32 + 31) {   // wave has unmasked work
        const char* KsB = LB + buf * 65536;
        const char* VsB = LB + 32768 + buf * 65536;

        // ---- S^T = K Q^T : keys [32v,32v+32), q-col = c31 ----
        f32x16 sacc = {};
        __builtin_amdgcn_s_setprio(1);
        #pragma unroll
        for (int ss = 0; ss < 8; ss++) {
          int row = v * 32 + c31;
          bf16x8 kf = *(const bf16x8*)(KsB + row * 256
                                       + ((ss * 32 + hi * 16) ^ ((row & 15) << 4)));
          sacc = __builtin_amdgcn_mfma_f32_32x32x16_bf16(kf, qf[ss], sacc, 0, 0, 0);
        }
        __builtin_amdgcn_s_setprio(0);

        // ---- per-q max over the wave's 32 keys (log2 domain) ----
        float t0[8];
        #pragma unroll
        for (int r = 0; r < 8; r++) t0[r] = fmaxf(sacc[r], sacc[r + 8]);
        #pragma unroll
        for (int d = 4; d > 0; d >>= 1)
          #pragma unroll
          for (int r = 0; r < 4; r++) if (r < d) t0[r] = fmaxf(t0[r], t0[r + d]);
        float mx = t0[0];
        i32x2 mm = __builtin_amdgcn_permlane32_swap(__float_as_int(mx), __float_as_int(mx),
                                                    false, false);
        mx = fmaxf(__int_as_float(mm.x), __int_as_float(mm.y));

        // ---- defer-max rescale (THR = 8/ln2 in log2 domain) ----
        if (__any(mx > m + 11.5416f)) {
          float mn = fmaxf(m, mx);
          float al = exp2r(m - mn);
          m = mn; l *= al;
          #pragma unroll
          for (int g = 0; g < 4; g++)
            #pragma unroll
            for (int r = 0; r < 16; r++) oacc[g][r] *= al;
        }

        // ---- exp2 + causal mask ----
        const int rel = qrow - kt * 128 - v * 32;     // keep key_local <= rel
        const bool maskT = (kt * 128 + v * 32 + 31) > (q0 + s * 32);
        #pragma unroll
        for (int r = 0; r < 16; r++) {
          float e = exp2r(sacc[r] - m);
          if (maskT) {
            int kl = (r & 3) + 8 * (r >> 2) + 4 * hi;
            e = (kl > rel) ? 0.f : e;
          }
          sacc[r] = e;
        }

        // ---- per-(hi,q) sum -> l ----
        float s0[8];
        #pragma unroll
        for (int r = 0; r < 8; r++) s0[r] = sacc[r] + sacc[r + 8];
        #pragma unroll
        for (int d = 4; d > 0; d >>= 1)
          #pragma unroll
          for (int r = 0; r < 4; r++) if (r < d) s0[r] = s0[r] + s0[r + d];
        l += s0[0];

        // ---- P^T B-fragments via cvt_pk + permlane32_swap (T12) ----
        bf16x8 pa[2];
        #pragma unroll
        for (int sg = 0; sg < 2; sg++) {
          int q0a = cvtpk(sacc[8 * sg + 0], sacc[8 * sg + 1]);
          int q1a = cvtpk(sacc[8 * sg + 2], sacc[8 * sg + 3]);
          int q0b = cvtpk(sacc[8 * sg + 4], sacc[8 * sg + 5]);
          int q1b = cvtpk(sacc[8 * sg + 6], sacc[8 * sg + 7]);
          i32x2 r0 = __builtin_amdgcn_permlane32_swap(q0a, q0b, false, false);
          i32x2 r1 = __builtin_amdgcn_permlane32_swap(q1a, q1b, false, false);
          union { int d[4]; bf16x8 vv; } u;
          u.d[0] = r0.x; u.d[1] = r1.x; u.d[2] = r0.y; u.d[3] = r1.y;
          pa[sg] = u.vv;
        }

        // ---- partial O^T += V^T P^T over keys [32v, 32v+32) ----
        __builtin_amdgcn_s_setprio(1);
        #pragma unroll
        for (int ks = 0; ks < 2; ks++)
          #pragma unroll
          for (int g = 0; g < 4; g++) {
            int row = g * 32 + c31;
            bf16x8 vf = *(const bf16x8*)(VsB + row * 256
                         + ((v * 64 + ks * 32 + hi * 16) ^ ((row & 15) << 4)));
            oacc[g] = __builtin_amdgcn_mfma_f32_32x32x16_bf16(vf, pa[ks], oacc[g], 0, 0, 0);
          }
        __builtin_amdgcn_s_setprio(0);
      }
      __syncthreads();   // staged loads landed; all waves done with buf
    }

    // ---- combine l across the hi pair (m already shared) ----
    i32x2 lr = __builtin_amdgcn_permlane32_swap(__float_as_int(l), __float_as_int(l),
                                                false, false);
    l = __int_as_float(lr.x) + __int_as_float(lr.y);

    // ---- 2-round merge of the 4 kv-quarter partials ----
    // round 1: v=1 -> region0, v=3 -> region1; v=0 folds r0, v=2 folds r1.
    // round 2: v=2 -> region0; v=0 folds r0, normalizes, writes O.
    auto publish = [&](int r) {
      float* Op = (float*)(LB + r * 65536) + s * 4096;
      #pragma unroll
      for (int g = 0; g < 4; g++)
        #pragma unroll
        for (int rr = 0; rr < 16; rr++) {
          int d = g * 32 + (rr & 3) + 8 * (rr >> 2) + 4 * hi;
          Op[d * 32 + c31] = oacc[g][rr];
        }
      if (hi == 0) {
        float* mm2 = (float*)(LB + 131072 + r * 1024) + (s * 32 + c31) * 2;
        mm2[0] = m; mm2[1] = l;
      }
    };
    auto fold = [&](int r) {
      const float* mm2 = (const float*)(LB + 131072 + r * 1024) + (s * 32 + c31) * 2;
      float lB = mm2[1];
      float mB = (lB > 0.f) ? mm2[0] : -3.0e38f;
      float ms = fmaxf(m, mB);
      float aA = exp2r(m - ms), aB = exp2r(mB - ms);
      const float* Op = (const float*)(LB + r * 65536) + s * 4096;
      #pragma unroll
      for (int g = 0; g < 4; g++)
        #pragma unroll
        for (int rr = 0; rr < 16; rr++) {
          int d = g * 32 + (rr & 3) + 8 * (rr >> 2) + 4 * hi;
          oacc[g][rr] = oacc[g][rr] * aA + Op[d * 32 + c31] * aB;
        }
      m = ms; l = l * aA + lB * aB;
    };

    if (v & 1) publish(v >> 1);
    __syncthreads();
    if (!(v & 1)) fold(v >> 1);
    __syncthreads();                 // v0 done reading r0 before v2 overwrites
    if (v == 2) publish(0);
    __syncthreads();
    if (v == 0) {
      fold(0);
      float inv = 1.0f / l;
      #pragma unroll
      for (int g = 0; g < 4; g++)
        #pragma unroll
        for (int tt = 0; tt < 4; tt++) {
          u32x2 pk;
          pk.x = (unsigned)cvtpk(oacc[g][4 * tt + 0] * inv, oacc[g][4 * tt + 1] * inv);
          pk.y = (unsigned)cvtpk(oacc[g][4 * tt + 2] * inv, oacc[g][4 * tt + 3] * inv);
          *(u32x2*)(O + (size_t)qrow * DM + h * HD + g * 32 + tt * 8 + hi * 4) = pk;
        }
    }
  }
}

extern "C" void kernel_launch(void* const* d_in, const int* in_sizes, int n_in,
                              void* d_out, int out_size, void* d_ws, size_t ws_size,
                              hipStream_t stream) {
  const float* x  = (const float*)d_in[0];
  const float* wq = (const float*)d_in[1];
  const float* wk = (const float*)d_in[2];
  const float* wv = (const float*)d_in[3];
  const float* wo = (const float*)d_in[4];
  float* out = (float*)d_out;

  const size_t SQDMs = (size_t)SEQ * DM;   // 8M elements
  short* Qb   = (short*)d_ws;
  short* Kb   = Qb + SQDMs;
  short* VTb  = Kb + SQDMs;
  short* Cb   = VTb + SQDMs;
  short* xbf  = Cb + SQDMs;
  short* wbuf = xbf + SQDMs;
  float2* tab = (float2*)(wbuf + (size_t)DM * DM);

  rope_tables_kernel<<<SEQ * 64 / 256, 256, 0, stream>>>(tab);
  f32_to_bf16_kernel<<<2048, 256, 0, stream>>>(x, xbf, (int)(SQDMs / 4));

  dim3 g(SEQ / 128, DM / 128);
  f32_to_bf16_kernel<<<2048, 256, 0, stream>>>(wq, wbuf, DM * DM / 4);
  gemm_rope_kernel<1><<<g, 256, 0, stream>>>(xbf, wbuf, Qb, tab);
  f32_to_bf16_kernel<<<2048, 256, 0, stream>>>(wk, wbuf, DM * DM / 4);
  gemm_rope_kernel<0><<<g, 256, 0, stream>>>(xbf, wbuf, Kb, tab);
  f32_to_bf16_kernel<<<2048, 256, 0, stream>>>(wv, wbuf, DM * DM / 4);
  gemm_async_kernel<2><<<g, 256, 0, stream>>>(xbf, wbuf, VTb, SEQ, DM, DM);

  flash_attn7_kernel<<<256, 1024, 0, stream>>>(Qb, Kb, VTb, Cb);

  f32_to_bf16_kernel<<<2048, 256, 0, stream>>>(wo, wbuf, DM * DM / 4);
  gemm_async_kernel<0><<<g, 256, 0, stream>>>(Cb, wbuf, out, SEQ, DM, DM);
}

// Round 9
// 299.837 us; speedup vs baseline: 1.5444x; 1.5348x over previous
//
#include <hip/hip_runtime.h>
#include <hip/hip_bf16.h>
#include <stdint.h>

#define SEQ 4096
#define DM 2048
#define NH 16
#define HD 128

typedef __attribute__((ext_vector_type(4)))  float f32x4;
typedef __attribute__((ext_vector_type(16))) float f32x16;
typedef __attribute__((ext_vector_type(8)))  short bf16x8;
typedef __attribute__((ext_vector_type(4)))  float float4_t;
typedef __attribute__((ext_vector_type(4)))  short s16x4;
typedef __attribute__((ext_vector_type(2)))  int   i32x2;
typedef __attribute__((ext_vector_type(2)))  unsigned u32x2;

__device__ __forceinline__ short f2bf(float f) {
  union { float f; unsigned u; } c; c.f = f;
  unsigned u = c.u;
  u += 0x7FFFu + ((u >> 16) & 1u);   // RNE
  return (short)(u >> 16);
}

__device__ __forceinline__ int cvtpk(float lo, float hi) {
  int r;
  asm("v_cvt_pk_bf16_f32 %0, %1, %2" : "=v"(r) : "v"(lo), "v"(hi));
  return r;
}

__device__ __forceinline__ float exp2r(float x) {   // raw v_exp_f32
  return __builtin_amdgcn_exp2f(x);
}

__device__ __forceinline__ void async16(const void* g, void* l) {
  __builtin_amdgcn_global_load_lds((const __attribute__((address_space(1))) void*)g,
                                   (__attribute__((address_space(3))) void*)l, 16, 0, 0);
}

__global__ __launch_bounds__(256) void rope_tables_kernel(float2* __restrict__ tab) {
  int idx = blockIdx.x * 256 + threadIdx.x;  // SEQ*64
  int s = idx >> 6, j = idx & 63;
  float invf = expf(-(float)j * (9.210340371976184f / 64.0f)); // 10000^(-j/64)
  float ang = (float)s * invf;
  tab[idx] = make_float2(cosf(ang), sinf(ang));
}

__global__ __launch_bounds__(256) void f32_to_bf16_kernel(const float* __restrict__ in,
                                                          short* __restrict__ out, int n4) {
  int stride = gridDim.x * 256;
  for (int i = blockIdx.x * 256 + threadIdx.x; i < n4; i += stride) {
    float4_t v = ((const float4_t*)in)[i];
    s16x4 r;
    #pragma unroll
    for (int u = 0; u < 4; u++) r[u] = f2bf(v[u]);
    ((s16x4*)out)[i] = r;
  }
}

// ---------------- GEMM: bf16 in, global_load_lds staging, BK=64 ------------
// C[M][N] = A[M][K] * B[N][K]^T. OUT_MODE: 0 f32, 2 bf16 transposed.
template<int OUT_MODE>
__global__ __launch_bounds__(256) void gemm_async_kernel(
    const short* __restrict__ A, const short* __restrict__ B,
    void* __restrict__ Cp, int M, int N, int K) {
  __shared__ short As[128 * 64];
  __shared__ short Bs[128 * 64];
  const int t = threadIdx.x, lane = t & 63, w = t >> 6;
  const int wr = w >> 1, wc = w & 1;
  const size_t Mbase = (size_t)blockIdx.x * 128;
  const size_t Nbase = (size_t)blockIdx.y * 128;
  f32x4 acc[4][4] = {};

  for (int k0 = 0; k0 < K; k0 += 64) {
    __syncthreads();
    #pragma unroll
    for (int c = 0; c < 4; c++) {
      int ob = w * 4096 + c * 1024;           // uniform per wave
      int o = ob + lane * 16;
      int row = o >> 7;
      int cb = (o & 127) ^ ((row & 7) << 4);
      async16((const char*)A + ((Mbase + row) * (size_t)K + k0) * 2 + cb, (char*)As + ob);
      async16((const char*)B + ((Nbase + row) * (size_t)K + k0) * 2 + cb, (char*)Bs + ob);
    }
    __syncthreads();

    bf16x8 a[2][4], b[2][4];
    #pragma unroll
    for (int ks = 0; ks < 2; ks++) {
      #pragma unroll
      for (int m = 0; m < 4; m++) {
        int row = wr * 64 + m * 16 + (lane & 15);
        int chunk = ks * 64 + (lane >> 4) * 16;
        a[ks][m] = *(const bf16x8*)((const char*)As + row * 128 + (chunk ^ ((row & 7) << 4)));
      }
      #pragma unroll
      for (int n = 0; n < 4; n++) {
        int row = wc * 64 + n * 16 + (lane & 15);
        int chunk = ks * 64 + (lane >> 4) * 16;
        b[ks][n] = *(const bf16x8*)((const char*)Bs + row * 128 + (chunk ^ ((row & 7) << 4)));
      }
    }
    #pragma unroll
    for (int ks = 0; ks < 2; ks++)
      #pragma unroll
      for (int m = 0; m < 4; m++)
        #pragma unroll
        for (int n = 0; n < 4; n++)
          acc[m][n] = __builtin_amdgcn_mfma_f32_16x16x32_bf16(a[ks][m], b[ks][n], acc[m][n], 0, 0, 0);
  }

  #pragma unroll
  for (int m = 0; m < 4; m++)
    #pragma unroll
    for (int n = 0; n < 4; n++)
      #pragma unroll
      for (int j = 0; j < 4; j++) {
        size_t row = Mbase + wr * 64 + m * 16 + (lane >> 4) * 4 + j;
        size_t col = Nbase + wc * 64 + n * 16 + (lane & 15);
        float v = acc[m][n][j];
        if (OUT_MODE == 0) ((float*)Cp)[row * N + col] = v;
        else               ((short*)Cp)[col * (size_t)M + row] = f2bf(v);
      }
}

// ---------------- GEMM + fused RoPE epilogue (Q/K projections) -------------
// Wave tiling 4x1: wave w owns rows w*32..w*32+31, all 128 cols (one head).
// IS_Q folds log2e/sqrt(HD) into Q so attention works in exp2 domain.
template<int IS_Q>
__global__ __launch_bounds__(256) void gemm_rope_kernel(
    const short* __restrict__ A, const short* __restrict__ B,
    short* __restrict__ C, const float2* __restrict__ tab) {
  __shared__ short As[128 * 64];
  __shared__ short Bs[128 * 64];
  const int t = threadIdx.x, lane = t & 63, w = t >> 6;
  const size_t Mbase = (size_t)blockIdx.x * 128;
  const size_t Nbase = (size_t)blockIdx.y * 128;
  const int K = DM;
  f32x4 acc[2][8] = {};

  for (int k0 = 0; k0 < K; k0 += 64) {
    __syncthreads();
    #pragma unroll
    for (int c = 0; c < 4; c++) {
      int ob = w * 4096 + c * 1024;
      int o = ob + lane * 16;
      int row = o >> 7;
      int cb = (o & 127) ^ ((row & 7) << 4);
      async16((const char*)A + ((Mbase + row) * (size_t)K + k0) * 2 + cb, (char*)As + ob);
      async16((const char*)B + ((Nbase + row) * (size_t)K + k0) * 2 + cb, (char*)Bs + ob);
    }
    __syncthreads();

    bf16x8 a[2][2], b[2][8];
    #pragma unroll
    for (int ks = 0; ks < 2; ks++) {
      #pragma unroll
      for (int m = 0; m < 2; m++) {
        int row = w * 32 + m * 16 + (lane & 15);
        int chunk = ks * 64 + (lane >> 4) * 16;
        a[ks][m] = *(const bf16x8*)((const char*)As + row * 128 + (chunk ^ ((row & 7) << 4)));
      }
      #pragma unroll
      for (int n = 0; n < 8; n++) {
        int row = n * 16 + (lane & 15);
        int chunk = ks * 64 + (lane >> 4) * 16;
        b[ks][n] = *(const bf16x8*)((const char*)Bs + row * 128 + (chunk ^ ((row & 7) << 4)));
      }
    }
    #pragma unroll
    for (int ks = 0; ks < 2; ks++)
      #pragma unroll
      for (int m = 0; m < 2; m++)
        #pragma unroll
        for (int n = 0; n < 8; n++)
          acc[m][n] = __builtin_amdgcn_mfma_f32_16x16x32_bf16(a[ks][m], b[ks][n], acc[m][n], 0, 0, 0);
  }

  // Q: scale = log2(e)/sqrt(128) so attention uses exp2 directly.
  const float SC = IS_Q ? 0.12751746f : 1.0f;
  #pragma unroll
  for (int m = 0; m < 2; m++)
    #pragma unroll
    for (int n = 0; n < 4; n++)
      #pragma unroll
      for (int j = 0; j < 4; j++) {
        int row = (int)Mbase + w * 32 + m * 16 + (lane >> 4) * 4 + j;   // seq pos
        int dj = n * 16 + (lane & 15);                                  // 0..63
        float2 cs = tab[row * 64 + dj];
        float cc = cs.x * SC, ss = cs.y * SC;
        float r1 = acc[m][n][j], r2 = acc[m][n + 4][j];
        C[(size_t)row * DM + Nbase + dj]      = f2bf(r1 * cc - r2 * ss);
        C[(size_t)row * DM + Nbase + dj + 64] = f2bf(r2 * cc + r1 * ss);
      }
}

// ---------------- flash attention v8: 512 thr, 2 blocks/CU -----------------
// 8 waves = 4 q-strips (32 rows) x 2 kv-halves (32 keys of KVBLK=64).
// LDS 66.5KB -> 2 blocks/CU -> 4 waves/SIMD (the VGPR-safe route: 512-thr
// blocks compile to 128 VGPR; 1024-thr blocks are hard-capped at 64 = spill).
// Grid 512 = 16 heads x 32 q-tiles (QBLK=128), no rep loop. Block mapping
// puts (qt=pr, qt=31-pr) at b and b+256 so linear round-robin co-residency
// pairs long+short tiles on one CU (66 kv-steps per CU either way).
// Q pre-scaled by log2e/sqrt(HD) (exp2 domain). VT is [DM][SEQ].
// S^T = mfma(K,Q); O^T = mfma(VT,P^T).
__global__ __launch_bounds__(512) void flash_attn8_kernel(
    const short* __restrict__ Q, const short* __restrict__ K,
    const short* __restrict__ VT, short* __restrict__ O) {
  // LDS: K buf b at b*16384 (64 rows x 256B); V^T buf b at 32768+b*16384
  // (128 d-rows x 128B). Merge overlay on [0,64K): [4 strip][128 d][32 q]
  // fp32; ml at 65536.
  __shared__ __align__(16) char LB[66560];
  const int t = threadIdx.x, lane = t & 63, w = t >> 6;   // w: 0..7
  const int hi = lane >> 5, c31 = lane & 31;
  const int s = w & 3, v = w >> 2;                // strip, kv-half
  const int id = blockIdx.x;                      // 0..511
  const int h  = (id & 7) * 2 + ((id >> 3) & 1);  // 2 heads per XCD
  const int pr = (id >> 4) & 15;                  // 0..15
  const int qt = (id < 256) ? pr : (31 - pr);     // 128-row q-tile

  auto stage = [&](int kt, int buf) {
    #pragma unroll
    for (int it = 0; it < 2; it++) {
      const int ob = it * 8192 + w * 1024;        // wave-uniform LDS byte base
      const int o  = ob + lane * 16;
      { const int row = o >> 8, x = o & 255;      // K: 64 rows x 256B
        const size_t src = ((size_t)(kt * 64 + row) * DM + h * HD) * 2
                         + (size_t)(x ^ ((row & 15) << 4));
        async16((const char*)K + src, LB + buf * 16384 + ob); }
      { const int row = o >> 7, x = o & 127;      // V^T: 128 d-rows x 128B
        const size_t src = ((size_t)(h * HD + row) * SEQ + (size_t)kt * 64) * 2
                         + (size_t)(x ^ ((row & 7) << 4));
        async16((const char*)VT + src, LB + 32768 + buf * 16384 + ob); }
    }
  };

  const int q0 = qt * 128;
  const int nt = 2 * (qt + 1);                    // 64-key tiles
  const int qrow = q0 + s * 32 + c31;             // this lane's q-row

  stage(0, 0);

  // Q fragments (B-operand): lane holds Q[qrow][16ss+8hi .. +7]
  bf16x8 qf[8];
  #pragma unroll
  for (int ss = 0; ss < 8; ss++)
    qf[ss] = *(const bf16x8*)(Q + (size_t)qrow * DM + h * HD + ss * 16 + hi * 8);

  f32x16 oacc[4] = {};
  float m = -3.0e38f, l = 0.f;

  __syncthreads();                                // stage(0) landed (vmcnt drain)

  for (int kt = 0; kt < nt; kt++) {
    const int buf = kt & 1;
    if (kt + 1 < nt) stage(kt + 1, buf ^ 1);

    if (kt * 64 + v * 32 <= q0 + s * 32 + 31) {   // wave has unmasked work
      const char* KsB = LB + buf * 16384;
      const char* VsB = LB + 32768 + buf * 16384;

      // ---- S^T = K Q^T : keys [32v,32v+32), q-col = c31 ----
      f32x16 sacc = {};
      __builtin_amdgcn_s_setprio(1);
      #pragma unroll
      for (int ss = 0; ss < 8; ss++) {
        int row = v * 32 + c31;
        bf16x8 kf = *(const bf16x8*)(KsB + row * 256
                                     + ((ss * 32 + hi * 16) ^ ((row & 15) << 4)));
        sacc = __builtin_amdgcn_mfma_f32_32x32x16_bf16(kf, qf[ss], sacc, 0, 0, 0);
      }
      __builtin_amdgcn_s_setprio(0);

      // ---- per-q max over the wave's 32 keys (log2 domain) ----
      float t0[8];
      #pragma unroll
      for (int r = 0; r < 8; r++) t0[r] = fmaxf(sacc[r], sacc[r + 8]);
      #pragma unroll
      for (int d = 4; d > 0; d >>= 1)
        #pragma unroll
        for (int r = 0; r < 4; r++) if (r < d) t0[r] = fmaxf(t0[r], t0[r + d]);
      float mx = t0[0];
      i32x2 mm = __builtin_amdgcn_permlane32_swap(__float_as_int(mx), __float_as_int(mx),
                                                  false, false);
      mx = fmaxf(__int_as_float(mm.x), __int_as_float(mm.y));

      // ---- defer-max rescale (THR = 8/ln2 in log2 domain) ----
      if (__any(mx > m + 11.5416f)) {
        float mn = fmaxf(m, mx);
        float al = exp2r(m - mn);
        m = mn; l *= al;
        #pragma unroll
        for (int g = 0; g < 4; g++)
          #pragma unroll
          for (int r = 0; r < 16; r++) oacc[g][r] *= al;
      }

      // ---- exp2 + causal mask ----
      const int rel = qrow - kt * 64 - v * 32;     // keep key_local <= rel
      const bool maskT = (kt * 64 + v * 32 + 31) > (q0 + s * 32);
      #pragma unroll
      for (int r = 0; r < 16; r++) {
        float e = exp2r(sacc[r] - m);
        if (maskT) {
          int kl = (r & 3) + 8 * (r >> 2) + 4 * hi;
          e = (kl > rel) ? 0.f : e;
        }
        sacc[r] = e;
      }

      // ---- per-(hi,q) sum -> l ----
      float s0[8];
      #pragma unroll
      for (int r = 0; r < 8; r++) s0[r] = sacc[r] + sacc[r + 8];
      #pragma unroll
      for (int d = 4; d > 0; d >>= 1)
        #pragma unroll
        for (int r = 0; r < 4; r++) if (r < d) s0[r] = s0[r] + s0[r + d];
      l += s0[0];

      // ---- P^T B-fragments via cvt_pk + permlane32_swap (T12) ----
      bf16x8 pa[2];
      #pragma unroll
      for (int sg = 0; sg < 2; sg++) {
        int q0a = cvtpk(sacc[8 * sg + 0], sacc[8 * sg + 1]);
        int q1a = cvtpk(sacc[8 * sg + 2], sacc[8 * sg + 3]);
        int q0b = cvtpk(sacc[8 * sg + 4], sacc[8 * sg + 5]);
        int q1b = cvtpk(sacc[8 * sg + 6], sacc[8 * sg + 7]);
        i32x2 r0 = __builtin_amdgcn_permlane32_swap(q0a, q0b, false, false);
        i32x2 r1 = __builtin_amdgcn_permlane32_swap(q1a, q1b, false, false);
        union { int d[4]; bf16x8 vv; } u;
        u.d[0] = r0.x; u.d[1] = r1.x; u.d[2] = r0.y; u.d[3] = r1.y;
        pa[sg] = u.vv;
      }

      // ---- partial O^T += V^T P^T over keys [32v, 32v+32) ----
      __builtin_amdgcn_s_setprio(1);
      #pragma unroll
      for (int ks = 0; ks < 2; ks++)
        #pragma unroll
        for (int g = 0; g < 4; g++) {
          int row = g * 32 + c31;
          bf16x8 vf = *(const bf16x8*)(VsB + row * 128
                       + ((v * 64 + ks * 32 + hi * 16) ^ ((row & 7) << 4)));
          oacc[g] = __builtin_amdgcn_mfma_f32_32x32x16_bf16(vf, pa[ks], oacc[g], 0, 0, 0);
        }
      __builtin_amdgcn_s_setprio(0);
    }
    __syncthreads();   // staged loads landed; all waves done with buf
  }

  // ---- combine l across the hi pair (m already shared) ----
  i32x2 lr = __builtin_amdgcn_permlane32_swap(__float_as_int(l), __float_as_int(l),
                                              false, false);
  l = __int_as_float(lr.x) + __int_as_float(lr.y);

  // ---- merge the 2 kv-half partials: v==1 publishes, v==0 folds+writes ----
  if (v == 1) {
    float* Op = (float*)LB + s * 4096;           // [128 d][32 q] per strip
    #pragma unroll
    for (int g = 0; g < 4; g++)
      #pragma unroll
      for (int rr = 0; rr < 16; rr++) {
        int d = g * 32 + (rr & 3) + 8 * (rr >> 2) + 4 * hi;
        Op[d * 32 + c31] = oacc[g][rr];
      }
    if (hi == 0) {
      float* mm2 = (float*)(LB + 65536) + (s * 32 + c31) * 2;
      mm2[0] = m; mm2[1] = l;
    }
  }
  __syncthreads();
  if (v == 0) {
    const float* mm2 = (const float*)(LB + 65536) + (s * 32 + c31) * 2;
    float lB = mm2[1];
    float mB = (lB > 0.f) ? mm2[0] : -3.0e38f;
    float ms = fmaxf(m, mB);
    float aA = exp2r(m - ms), aB = exp2r(mB - ms);
    float linv = 1.0f / (l * aA + lB * aB);
    float sA = aA * linv, sB = aB * linv;
    const float* Op = (const float*)LB + s * 4096;
    #pragma unroll
    for (int g = 0; g < 4; g++)
      #pragma unroll
      for (int tt = 0; tt < 4; tt++) {
        float o[4];
        #pragma unroll
        for (int e = 0; e < 4; e++) {
          int d = g * 32 + e + 8 * tt + 4 * hi;
          o[e] = oacc[g][4 * tt + e] * sA + Op[d * 32 + c31] * sB;
        }
        u32x2 pk;
        pk.x = (unsigned)cvtpk(o[0], o[1]);
        pk.y = (unsigned)cvtpk(o[2], o[3]);
        *(u32x2*)(O + (size_t)qrow * DM + h * HD + g * 32 + tt * 8 + hi * 4) = pk;
      }
  }
}

extern "C" void kernel_launch(void* const* d_in, const int* in_sizes, int n_in,
                              void* d_out, int out_size, void* d_ws, size_t ws_size,
                              hipStream_t stream) {
  const float* x  = (const float*)d_in[0];
  const float* wq = (const float*)d_in[1];
  const float* wk = (const float*)d_in[2];
  const float* wv = (const float*)d_in[3];
  const float* wo = (const float*)d_in[4];
  float* out = (float*)d_out;

  const size_t SQDMs = (size_t)SEQ * DM;   // 8M elements
  short* Qb   = (short*)d_ws;
  short* Kb   = Qb + SQDMs;
  short* VTb  = Kb + SQDMs;
  short* Cb   = VTb + SQDMs;
  short* xbf  = Cb + SQDMs;
  short* wbuf = xbf + SQDMs;
  float2* tab = (float2*)(wbuf + (size_t)DM * DM);

  rope_tables_kernel<<<SEQ * 64 / 256, 256, 0, stream>>>(tab);
  f32_to_bf16_kernel<<<2048, 256, 0, stream>>>(x, xbf, (int)(SQDMs / 4));

  dim3 g(SEQ / 128, DM / 128);
  f32_to_bf16_kernel<<<2048, 256, 0, stream>>>(wq, wbuf, DM * DM / 4);
  gemm_rope_kernel<1><<<g, 256, 0, stream>>>(xbf, wbuf, Qb, tab);
  f32_to_bf16_kernel<<<2048, 256, 0, stream>>>(wk, wbuf, DM * DM / 4);
  gemm_rope_kernel<0><<<g, 256, 0, stream>>>(xbf, wbuf, Kb, tab);
  f32_to_bf16_kernel<<<2048, 256, 0, stream>>>(wv, wbuf, DM * DM / 4);
  gemm_async_kernel<2><<<g, 256, 0, stream>>>(xbf, wbuf, VTb, SEQ, DM, DM);

  flash_attn8_kernel<<<512, 512, 0, stream>>>(Qb, Kb, VTb, Cb);

  f32_to_bf16_kernel<<<2048, 256, 0, stream>>>(wo, wbuf, DM * DM / 4);
  gemm_async_kernel<0><<<g, 256, 0, stream>>>(Cb, wbuf, out, SEQ, DM, DM);
}